// Round 1
// baseline (5203.383 us; speedup 1.0000x reference)
//
#include <hip/hip_runtime.h>
#include <float.h>

#define DIMC 384
#define NHC 6
#define DHC 64
#define INNERC 384
#define HIDC 1536
#define NBC 7
#define S_TOT 1600

// ---------------- reduction helpers ----------------
__device__ __forceinline__ float waveReduceSumF(float v){
  #pragma unroll
  for (int o = 32; o >= 1; o >>= 1) v += __shfl_xor(v, o);
  return v;
}
__device__ __forceinline__ float waveReduceMaxF(float v){
  #pragma unroll
  for (int o = 32; o >= 1; o >>= 1) v = fmaxf(v, __shfl_xor(v, o));
  return v;
}
__device__ __forceinline__ int waveReduceSumI(int v){
  #pragma unroll
  for (int o = 32; o >= 1; o >>= 1) v += __shfl_xor(v, o);
  return v;
}
// 256-thread block reductions, broadcast result to all threads
__device__ __forceinline__ float blockReduceSumF256(float v, float* scr){
  v = waveReduceSumF(v);
  int wid = threadIdx.x >> 6;
  __syncthreads();
  if ((threadIdx.x & 63) == 0) scr[wid] = v;
  __syncthreads();
  return scr[0] + scr[1] + scr[2] + scr[3];
}
__device__ __forceinline__ float blockReduceMaxF256(float v, float* scr){
  v = waveReduceMaxF(v);
  int wid = threadIdx.x >> 6;
  __syncthreads();
  if ((threadIdx.x & 63) == 0) scr[wid] = v;
  __syncthreads();
  return fmaxf(fmaxf(scr[0], scr[1]), fmaxf(scr[2], scr[3]));
}
__device__ __forceinline__ int blockReduceSumI256(int v, int* scr){
  v = waveReduceSumI(v);
  int wid = threadIdx.x >> 6;
  __syncthreads();
  if ((threadIdx.x & 63) == 0) scr[wid] = v;
  __syncthreads();
  return scr[0] + scr[1] + scr[2] + scr[3];
}

// ---------------- simple copy ----------------
__global__ void copy_kernel(const float* __restrict__ in, float* __restrict__ out, int n){
  int i = blockIdx.x * 256 + threadIdx.x;
  if (i < n) out[i] = in[i];
}

// ---------------- LayerNorm (one row per block, 128 threads) ----------------
__global__ __launch_bounds__(128) void ln_kernel(const float* __restrict__ in,
                                                 const float* __restrict__ g,
                                                 const float* __restrict__ b,
                                                 float* __restrict__ out){
  int row = blockIdx.x;
  int tid = threadIdx.x;
  const float* rp = in + (size_t)row * DIMC;
  float x0 = rp[tid], x1 = rp[tid + 128], x2 = rp[tid + 256];
  float s  = x0 + x1 + x2;
  float sq = x0 * x0 + x1 * x1 + x2 * x2;
  __shared__ float scr0[2], scr1[2];
  s  = waveReduceSumF(s);
  sq = waveReduceSumF(sq);
  int wid = tid >> 6;
  if ((tid & 63) == 0){ scr0[wid] = s; scr1[wid] = sq; }
  __syncthreads();
  float S1 = scr0[0] + scr0[1];
  float S2 = scr1[0] + scr1[1];
  float mean = S1 * (1.f / DIMC);
  float var  = S2 * (1.f / DIMC) - mean * mean;
  float inv  = rsqrtf(var + 1e-5f);
  float* op = out + (size_t)row * DIMC;
  op[tid]       = (x0 - mean) * inv * g[tid]       + b[tid];
  op[tid + 128] = (x1 - mean) * inv * g[tid + 128] + b[tid + 128];
  op[tid + 256] = (x2 - mean) * inv * g[tid + 256] + b[tid + 256];
}

// ---------------- tiled fp32 GEMM: C[M,N] = act(A[M,K]@B[K,N] + bias) + res ----------------
template<int ACT, bool HAS_BIAS, bool HAS_RES>
__global__ __launch_bounds__(256) void gemm_kernel(const float* __restrict__ A,
                                                   const float* __restrict__ B,
                                                   const float* __restrict__ bias,
                                                   const float* __restrict__ res,
                                                   float* __restrict__ C,
                                                   int M, int N, int K){
  const int BM = 64, BN = 64, BK = 16;
  __shared__ float As[BK][BM];
  __shared__ float Bs[BK][BN];
  int tid = threadIdx.x;
  int tx = tid & 15, ty = tid >> 4;
  int row0 = blockIdx.y * BM, col0 = blockIdx.x * BN;
  float acc[4][4] = {};
  for (int k0 = 0; k0 < K; k0 += BK){
    #pragma unroll
    for (int it = 0; it < 4; ++it){
      int e = tid + it * 256;
      int r  = e >> 4, kk  = e & 15;
      As[kk][r] = A[(size_t)(row0 + r) * K + k0 + kk];
      int kk2 = e >> 6, c = e & 63;
      Bs[kk2][c] = B[(size_t)(k0 + kk2) * N + col0 + c];
    }
    __syncthreads();
    #pragma unroll
    for (int kk = 0; kk < BK; ++kk){
      float a[4], bv[4];
      #pragma unroll
      for (int i = 0; i < 4; ++i) a[i]  = As[kk][ty * 4 + i];
      #pragma unroll
      for (int j = 0; j < 4; ++j) bv[j] = Bs[kk][tx * 4 + j];
      #pragma unroll
      for (int i = 0; i < 4; ++i)
        #pragma unroll
        for (int j = 0; j < 4; ++j) acc[i][j] += a[i] * bv[j];
    }
    __syncthreads();
  }
  #pragma unroll
  for (int i = 0; i < 4; ++i){
    int r = row0 + ty * 4 + i;
    #pragma unroll
    for (int j = 0; j < 4; ++j){
      int c = col0 + tx * 4 + j;
      float v = acc[i][j];
      if (HAS_BIAS) v += bias[c];
      if (ACT == 1) v = (v >= 0.f) ? v : 0.2f * v;
      if (HAS_RES) v += res[(size_t)r * N + c];
      C[(size_t)r * N + c] = v;
    }
  }
}

// ---------------- repack qkv stride-3 interleave into [h][s][d] panels ----------------
__global__ void repack_kernel(const float* __restrict__ qkv, float* __restrict__ Qt,
                              float* __restrict__ Kt, float* __restrict__ Vt){
  int idx = blockIdx.x * 256 + threadIdx.x;
  if (idx >= S_TOT * INNERC) return;
  int s = idx / INNERC, hd = idx % INNERC;
  int h = hd >> 6, d = hd & 63;
  const float* p = qkv + (size_t)s * 3 * INNERC + 3 * hd;
  size_t o = (size_t)h * S_TOT * DHC + (size_t)s * DHC + d;
  Qt[o] = p[0];
  Kt[o] = p[1];
  Vt[o] = p[2];
}

// ---------------- fused attention: one block per (query row, head) ----------------
__global__ __launch_bounds__(256) void attn_kernel(const float* __restrict__ Qt,
                                                   const float* __restrict__ Kt,
                                                   const float* __restrict__ Vt,
                                                   const float* __restrict__ rel_bias,
                                                   const int* __restrict__ Wp,
                                                   const int* __restrict__ topk_p,
                                                   float* __restrict__ out){
  const int sq = blockIdx.x;   // 0..1599 query index
  const int hh = blockIdx.y;   // 0..5 head
  const int tid = threadIdx.x;

  __shared__ float row[S_TOT];
  __shared__ unsigned urow[S_TOT];
  __shared__ float qs[DHC];
  __shared__ float qb[NBC * NBC];
  __shared__ float pvp[4][DHC];
  __shared__ float fscr[4];
  __shared__ int   iscr[4];

  const float* Qh = Qt + (size_t)hh * S_TOT * DHC;
  const float* Kh = Kt + (size_t)hh * S_TOT * DHC;
  const float* Vh = Vt + (size_t)hh * S_TOT * DHC;

  if (tid < DHC) qs[tid] = Qh[(size_t)sq * DHC + tid];
  __syncthreads();

  // qb[nb] = q . rel_bias[nb]   (49 buckets)
  for (int nb = tid; nb < NBC * NBC; nb += 256){
    const float* rb = rel_bias + (size_t)nb * DHC;
    float sum = 0.f;
    #pragma unroll 8
    for (int d = 0; d < DHC; ++d) sum += qs[d] * rb[d];
    qb[nb] = sum;
  }
  __syncthreads();

  const float scale = 0.05103103630798287f; // 384^-0.5
  const int Wv = *Wp;                        // 40
  const int qv = sq / Wv, qh = sq % Wv;
  const int half = NBC / 2;                  // 3

  float lm = -FLT_MAX;
  for (int k = tid; k < S_TOT; k += 256){
    const float* kp = Kh + (size_t)k * DHC;
    float dot = 0.f;
    #pragma unroll 8
    for (int d = 0; d < DHC; ++d) dot += qs[d] * kp[d];
    int kv = k / Wv, kh = k % Wv;
    int dv = kv - qv, dh = kh - qh;
    int man = (dv < 0 ? -dv : dv) + (dh < 0 ? -dh : dh);
    float bv = (man <= half) ? qb[(dv + half) * NBC + (dh + half)] : qb[0];
    float sc = (dot + bv) * scale;
    row[k] = sc;
    unsigned ub = __float_as_uint(sc);
    urow[k] = (ub & 0x80000000u) ? ~ub : (ub | 0x80000000u);
    lm = fmaxf(lm, sc);
  }
  float m = blockReduceMaxF256(lm, fscr);

  // exact kth-largest (counting duplicates) via MSB-first radix select
  int kwant = *topk_p;
  if (kwant > S_TOT) kwant = S_TOT;
  unsigned prefix = 0; int greater = 0;
  for (int b = 31; b >= 0; --b){
    unsigned want = (prefix >> b) | 1u;
    int cnt = 0;
    for (int k = tid; k < S_TOT; k += 256) cnt += ((urow[k] >> b) == want);
    cnt = blockReduceSumI256(cnt, iscr);
    if (greater + cnt >= kwant) prefix |= (1u << b);
    else greater += cnt;
  }

  // masked softmax numerators
  float lsum = 0.f;
  for (int k = tid; k < S_TOT; k += 256){
    float p = (urow[k] >= prefix) ? __expf(row[k] - m) : 0.f;
    row[k] = p;
    lsum += p;
  }
  float denom = blockReduceSumF256(lsum, fscr);  // includes barrier: row[] now visible

  // PV: 4 groups of 64 lanes; lane d accumulates over its group's k range
  int d = tid & 63, g = tid >> 6;
  float acc = 0.f;
  const int span = S_TOT / 4;
  for (int k = g * span; k < (g + 1) * span; ++k)
    acc += row[k] * Vh[(size_t)k * DHC + d];
  pvp[g][d] = acc;
  __syncthreads();
  if (tid < DHC){
    float v = (pvp[0][tid] + pvp[1][tid] + pvp[2][tid] + pvp[3][tid]) / denom;
    out[(size_t)sq * INNERC + hh * DHC + tid] = v;
  }
}

extern "C" void kernel_launch(void* const* d_in, const int* in_sizes, int n_in,
                              void* d_out, int out_size, void* d_ws, size_t ws_size,
                              hipStream_t stream) {
  const float* x       = (const float*)d_in[0];
  const float* W_qkv   = (const float*)d_in[1];
  const float* W_o     = (const float*)d_in[2];
  const float* ln1_g   = (const float*)d_in[3];
  const float* ln1_b   = (const float*)d_in[4];
  const float* ln2_g   = (const float*)d_in[5];
  const float* ln2_b   = (const float*)d_in[6];
  const float* rel_bias= (const float*)d_in[7];
  const float* ff_w1   = (const float*)d_in[8];
  const float* ff_b1   = (const float*)d_in[9];
  const float* ff_w2   = (const float*)d_in[10];
  const float* ff_b2   = (const float*)d_in[11];
  const int*   Wp      = (const int*)d_in[13];
  const int*   topk_p  = (const int*)d_in[14];

  float* h = (float*)d_out;   // residual stream lives in d_out

  char* ws = (char*)d_ws;
  float* n_buf = (float*)ws;                 ws += (size_t)S_TOT * DIMC * 4;       // 2.46 MB
  float* qkv   = (float*)ws;                 // 7.37 MB
  float* y1    = (float*)ws;                 // alias: y1 (9.83 MB) overlaps qkv+Qt (both dead by FF1)
                                             ws += (size_t)S_TOT * 3 * INNERC * 4;
  float* Qt    = (float*)ws;                 ws += (size_t)NHC * S_TOT * DHC * 4;  // 2.46 MB
  float* Kt    = (float*)ws;                 ws += (size_t)NHC * S_TOT * DHC * 4;
  float* Vt    = (float*)ws;                 ws += (size_t)NHC * S_TOT * DHC * 4;
  float* attn_out = (float*)ws;              ws += (size_t)S_TOT * INNERC * 4;

  // h = x
  copy_kernel<<<(S_TOT * DIMC + 255) / 256, 256, 0, stream>>>(x, h, S_TOT * DIMC);

  for (int l = 0; l < 6; ++l){
    const float* wqkv = W_qkv + (size_t)l * DIMC * 3 * INNERC;
    const float* wo   = W_o   + (size_t)l * INNERC * DIMC;
    const float* w1   = ff_w1 + (size_t)l * DIMC * HIDC;
    const float* w2   = ff_w2 + (size_t)l * HIDC * DIMC;

    // n = LN(h)
    ln_kernel<<<S_TOT, 128, 0, stream>>>(h, ln1_g + l * DIMC, ln1_b + l * DIMC, n_buf);
    // qkv = n @ Wqkv
    gemm_kernel<0, false, false><<<dim3(3 * INNERC / 64, S_TOT / 64), 256, 0, stream>>>(
        n_buf, wqkv, nullptr, nullptr, qkv, S_TOT, 3 * INNERC, DIMC);
    // de-interleave into per-head panels
    repack_kernel<<<(S_TOT * INNERC + 255) / 256, 256, 0, stream>>>(qkv, Qt, Kt, Vt);
    // fused attention (scores + contextual bias + top-k + softmax + PV)
    attn_kernel<<<dim3(S_TOT, NHC), 256, 0, stream>>>(Qt, Kt, Vt, rel_bias, Wp, topk_p, attn_out);
    // h += attn_out @ Wo
    gemm_kernel<0, false, true><<<dim3(DIMC / 64, S_TOT / 64), 256, 0, stream>>>(
        attn_out, wo, nullptr, h, h, S_TOT, DIMC, INNERC);
    // n = LN(h)
    ln_kernel<<<S_TOT, 128, 0, stream>>>(h, ln2_g + l * DIMC, ln2_b + l * DIMC, n_buf);
    // y1 = leaky_relu(n @ w1 + b1)
    gemm_kernel<1, true, false><<<dim3(HIDC / 64, S_TOT / 64), 256, 0, stream>>>(
        n_buf, w1, ff_b1 + l * HIDC, nullptr, y1, S_TOT, HIDC, DIMC);
    // h += y1 @ w2 + b2
    gemm_kernel<0, true, true><<<dim3(DIMC / 64, S_TOT / 64), 256, 0, stream>>>(
        y1, w2, ff_b2 + l * DIMC, h, h, S_TOT, DIMC, HIDC);
  }
}

// Round 2
// 2844.792 us; speedup vs baseline: 1.8291x; 1.8291x over previous
//
#include <hip/hip_runtime.h>
#include <float.h>

#define DIMC 384
#define NHC 6
#define DHC 64
#define INNERC 384
#define HIDC 1536
#define NBC 7
#define S_TOT 1600
#define CAPC 256

// ---------------- reduction helpers ----------------
__device__ __forceinline__ float waveReduceSumF(float v){
  #pragma unroll
  for (int o = 32; o >= 1; o >>= 1) v += __shfl_xor(v, o);
  return v;
}
__device__ __forceinline__ float waveReduceMaxF(float v){
  #pragma unroll
  for (int o = 32; o >= 1; o >>= 1) v = fmaxf(v, __shfl_xor(v, o));
  return v;
}
__device__ __forceinline__ float blockReduceSumF256(float v, float* scr){
  v = waveReduceSumF(v);
  int wid = threadIdx.x >> 6;
  __syncthreads();
  if ((threadIdx.x & 63) == 0) scr[wid] = v;
  __syncthreads();
  return scr[0] + scr[1] + scr[2] + scr[3];
}
__device__ __forceinline__ float blockReduceMaxF256(float v, float* scr){
  v = waveReduceMaxF(v);
  int wid = threadIdx.x >> 6;
  __syncthreads();
  if ((threadIdx.x & 63) == 0) scr[wid] = v;
  __syncthreads();
  return fmaxf(fmaxf(scr[0], scr[1]), fmaxf(scr[2], scr[3]));
}

__device__ __forceinline__ unsigned fkey(float x){
  unsigned u = __float_as_uint(x);
  return (u & 0x80000000u) ? ~u : (u | 0x80000000u);
}

// ---------------- simple copy ----------------
__global__ void copy_kernel(const float* __restrict__ in, float* __restrict__ out, int n){
  int i = blockIdx.x * 256 + threadIdx.x;
  if (i < n) out[i] = in[i];
}

// ---------------- LayerNorm (one row per block, 128 threads) ----------------
__global__ __launch_bounds__(128) void ln_kernel(const float* __restrict__ in,
                                                 const float* __restrict__ g,
                                                 const float* __restrict__ b,
                                                 float* __restrict__ out){
  int row = blockIdx.x;
  int tid = threadIdx.x;
  const float* rp = in + (size_t)row * DIMC;
  float x0 = rp[tid], x1 = rp[tid + 128], x2 = rp[tid + 256];
  float s  = x0 + x1 + x2;
  float sq = x0 * x0 + x1 * x1 + x2 * x2;
  __shared__ float scr0[2], scr1[2];
  s  = waveReduceSumF(s);
  sq = waveReduceSumF(sq);
  int wid = tid >> 6;
  if ((tid & 63) == 0){ scr0[wid] = s; scr1[wid] = sq; }
  __syncthreads();
  float S1 = scr0[0] + scr0[1];
  float S2 = scr1[0] + scr1[1];
  float mean = S1 * (1.f / DIMC);
  float var  = S2 * (1.f / DIMC) - mean * mean;
  float inv  = rsqrtf(var + 1e-5f);
  float* op = out + (size_t)row * DIMC;
  op[tid]       = (x0 - mean) * inv * g[tid]       + b[tid];
  op[tid + 128] = (x1 - mean) * inv * g[tid + 128] + b[tid + 128];
  op[tid + 256] = (x2 - mean) * inv * g[tid + 256] + b[tid + 256];
}

// ---------------- tiled fp32 GEMM: C[M,N] = act(A[M,K]@B[K,N] + bias) + res ----------------
template<int ACT, bool HAS_BIAS, bool HAS_RES>
__global__ __launch_bounds__(256) void gemm_kernel(const float* __restrict__ A,
                                                   const float* __restrict__ B,
                                                   const float* __restrict__ bias,
                                                   const float* __restrict__ res,
                                                   float* __restrict__ C,
                                                   int M, int N, int K){
  const int BM = 64, BN = 64, BK = 16;
  __shared__ float As[BK][BM];
  __shared__ float Bs[BK][BN];
  int tid = threadIdx.x;
  int tx = tid & 15, ty = tid >> 4;
  int row0 = blockIdx.y * BM, col0 = blockIdx.x * BN;
  float acc[4][4] = {};
  for (int k0 = 0; k0 < K; k0 += BK){
    #pragma unroll
    for (int it = 0; it < 4; ++it){
      int e = tid + it * 256;
      int r  = e >> 4, kk  = e & 15;
      As[kk][r] = A[(size_t)(row0 + r) * K + k0 + kk];
      int kk2 = e >> 6, c = e & 63;
      Bs[kk2][c] = B[(size_t)(k0 + kk2) * N + col0 + c];
    }
    __syncthreads();
    #pragma unroll
    for (int kk = 0; kk < BK; ++kk){
      float a[4], bv[4];
      #pragma unroll
      for (int i = 0; i < 4; ++i) a[i]  = As[kk][ty * 4 + i];
      #pragma unroll
      for (int j = 0; j < 4; ++j) bv[j] = Bs[kk][tx * 4 + j];
      #pragma unroll
      for (int i = 0; i < 4; ++i)
        #pragma unroll
        for (int j = 0; j < 4; ++j) acc[i][j] += a[i] * bv[j];
    }
    __syncthreads();
  }
  #pragma unroll
  for (int i = 0; i < 4; ++i){
    int r = row0 + ty * 4 + i;
    #pragma unroll
    for (int j = 0; j < 4; ++j){
      int c = col0 + tx * 4 + j;
      float v = acc[i][j];
      if (HAS_BIAS) v += bias[c];
      if (ACT == 1) v = (v >= 0.f) ? v : 0.2f * v;
      if (HAS_RES) v += res[(size_t)r * N + c];
      C[(size_t)r * N + c] = v;
    }
  }
}

// ---------------- repack qkv stride-3 interleave into [h][s][d] panels ----------------
__global__ void repack_kernel(const float* __restrict__ qkv, float* __restrict__ Qt,
                              float* __restrict__ Kt, float* __restrict__ Vt){
  int idx = blockIdx.x * 256 + threadIdx.x;
  if (idx >= S_TOT * INNERC) return;
  int s = idx / INNERC, hd = idx % INNERC;
  int h = hd >> 6, d = hd & 63;
  const float* p = qkv + (size_t)s * 3 * INNERC + 3 * hd;
  size_t o = (size_t)h * S_TOT * DHC + (size_t)s * DHC + d;
  Qt[o] = p[0];
  Kt[o] = p[1];
  Vt[o] = p[2];
}

// ---------------- fused attention: one block per (query row, head) ----------------
// 256 threads. 4 lanes per K-row (each lane owns a 16-float q fragment in regs).
__global__ __launch_bounds__(256) void attn_kernel(const float* __restrict__ Qt,
                                                   const float* __restrict__ Kt,
                                                   const float* __restrict__ Vt,
                                                   const float* __restrict__ rel_bias,
                                                   const int* __restrict__ Wp,
                                                   const int* __restrict__ topk_p,
                                                   float* __restrict__ out){
  const int sq = blockIdx.x;   // query index
  const int hh = blockIdx.y;   // head
  const int tid = threadIdx.x;
  const int frag = tid & 3;    // which 16-float fragment of d
  const int lane = tid & 63;

  __shared__ float row[S_TOT];
  __shared__ float qb[NBC * NBC];
  __shared__ int   hist[256];
  __shared__ int   idxs[CAPC];
  __shared__ float pcomp[CAPC];
  __shared__ float pvp[4][DHC];
  __shared__ float fscr[4];
  __shared__ int   iscr[2];
  __shared__ int   cnt_s;

  const float* Qh = Qt + (size_t)hh * S_TOT * DHC;
  const float* Kh = Kt + (size_t)hh * S_TOT * DHC;
  const float* Vh = Vt + (size_t)hh * S_TOT * DHC;

  // q fragment into registers (16 floats)
  float qreg[16];
  {
    const float4* qp = (const float4*)(Qh + (size_t)sq * DHC + frag * 16);
    #pragma unroll
    for (int i = 0; i < 4; ++i){
      float4 v = qp[i];
      qreg[4*i+0] = v.x; qreg[4*i+1] = v.y; qreg[4*i+2] = v.z; qreg[4*i+3] = v.w;
    }
  }

  // qb[nb] = q . rel_bias[nb]  (49 buckets, 4 lanes each)
  if (tid < 4 * NBC * NBC){
    int nb = tid >> 2;
    const float4* rp = (const float4*)(rel_bias + (size_t)nb * DHC + frag * 16);
    float p = 0.f;
    #pragma unroll
    for (int i = 0; i < 4; ++i){
      float4 v = rp[i];
      p += qreg[4*i+0]*v.x + qreg[4*i+1]*v.y + qreg[4*i+2]*v.z + qreg[4*i+3]*v.w;
    }
    p += __shfl_xor(p, 1);
    p += __shfl_xor(p, 2);
    if (frag == 0) qb[nb] = p;
  }
  __syncthreads();

  const float scale = 0.05103103630798287f; // 384^-0.5
  const int Wv = *Wp;                        // 40
  const int qv = sq / Wv, qh = sq % Wv;
  const int half = NBC / 2;                  // 3
  const int kwant_raw = *topk_p;
  const int kwant = (kwant_raw > S_TOT) ? S_TOT : kwant_raw;

  // ---- scores: 64 K-rows per iteration, coalesced float4 loads ----
  float lm = -FLT_MAX;
  const int krow = tid >> 2;                 // 0..63
  #pragma unroll 1
  for (int i = 0; i < S_TOT / 64; ++i){
    int k = i * 64 + krow;
    const float4* kp = (const float4*)(Kh + (size_t)k * DHC + frag * 16);
    float dot = 0.f;
    #pragma unroll
    for (int j = 0; j < 4; ++j){
      float4 v = kp[j];
      dot += qreg[4*j+0]*v.x + qreg[4*j+1]*v.y + qreg[4*j+2]*v.z + qreg[4*j+3]*v.w;
    }
    dot += __shfl_xor(dot, 1);
    dot += __shfl_xor(dot, 2);
    if (frag == 0){
      int kv = k / Wv, kh = k % Wv;
      int dv = kv - qv, dh = kh - qh;
      int man = (dv < 0 ? -dv : dv) + (dh < 0 ? -dh : dh);
      float bv = (man <= half) ? qb[(dv + half) * NBC + (dh + half)] : qb[0];
      float sc = (dot + bv) * scale;
      row[k] = sc;
      lm = fmaxf(lm, sc);
    }
  }
  float m = blockReduceMaxF256(lm, fscr);  // also makes row[] visible

  // ---- exact kth-largest via 8-bit-digit radix select (4 passes) ----
  unsigned prefix = 0;
  int greater = 0;
  #pragma unroll 1
  for (int pass = 0; pass < 4; ++pass){
    const int shift = 24 - 8 * pass;
    hist[tid] = 0;
    __syncthreads();
    for (int k = tid; k < S_TOT; k += 256){
      unsigned u = fkey(row[k]);
      bool match = (pass == 0) || ((u >> (shift + 8)) == (prefix >> (shift + 8)));
      if (match) atomicAdd(&hist[(u >> shift) & 255], 1);
    }
    __syncthreads();
    if (tid < 64){
      int v0 = hist[tid*4], v1 = hist[tid*4+1], v2 = hist[tid*4+2], v3 = hist[tid*4+3];
      int s3 = v3, s2 = v2 + s3, s1 = v1 + s2, s0 = v0 + s1;
      int t = s0;
      #pragma unroll
      for (int off = 1; off < 64; off <<= 1){
        int o = __shfl_down(t, off);
        if (lane + off < 64) t += o;
      }
      int above = t - s0;                    // sum of bins in lanes > this lane
      int need = kwant - greater;
      int suf0 = above + s0, suf1 = above + s1, suf2 = above + s2, suf3 = above + s3;
      if (suf0 >= need && suf1 <  need){ iscr[0] = 4*tid+0; iscr[1] = suf1; }
      if (suf1 >= need && suf2 <  need){ iscr[0] = 4*tid+1; iscr[1] = suf2; }
      if (suf2 >= need && suf3 <  need){ iscr[0] = 4*tid+2; iscr[1] = suf3; }
      if (suf3 >= need && above <  need){ iscr[0] = 4*tid+3; iscr[1] = above; }
    }
    __syncthreads();
    prefix |= ((unsigned)iscr[0]) << shift;
    greater += iscr[1];
    __syncthreads();
  }
  // prefix == sortable key of the kth-largest score; keep fkey(x) >= prefix

  // ---- compact survivors, exp only those ----
  if (tid == 0) cnt_s = 0;
  __syncthreads();
  float lsum = 0.f;
  for (int k = tid; k < S_TOT; k += 256){
    float sc = row[k];
    if (fkey(sc) >= prefix){
      float p = __expf(sc - m);
      lsum += p;
      int pos = atomicAdd(&cnt_s, 1);
      if (pos < CAPC){ idxs[pos] = k; pcomp[pos] = p; }
    }
  }
  float denom = blockReduceSumF256(lsum, fscr);
  int cnt = cnt_s;

  // ---- PV ----
  const int d = tid & 63, g = tid >> 6;
  float acc = 0.f;
  if (cnt <= CAPC){
    for (int j = g; j < cnt; j += 4)
      acc += pcomp[j] * Vh[(size_t)idxs[j] * DHC + d];
  } else {
    // pathological all-ties fallback: dense masked PV
    const int span = S_TOT / 4;
    for (int k = g * span; k < (g + 1) * span; ++k){
      float sc = row[k];
      float p = (fkey(sc) >= prefix) ? __expf(sc - m) : 0.f;
      acc += p * Vh[(size_t)k * DHC + d];
    }
  }
  pvp[g][d] = acc;
  __syncthreads();
  if (tid < DHC){
    float v = (pvp[0][tid] + pvp[1][tid] + pvp[2][tid] + pvp[3][tid]) / denom;
    out[(size_t)sq * INNERC + hh * DHC + tid] = v;
  }
}

extern "C" void kernel_launch(void* const* d_in, const int* in_sizes, int n_in,
                              void* d_out, int out_size, void* d_ws, size_t ws_size,
                              hipStream_t stream) {
  const float* x       = (const float*)d_in[0];
  const float* W_qkv   = (const float*)d_in[1];
  const float* W_o     = (const float*)d_in[2];
  const float* ln1_g   = (const float*)d_in[3];
  const float* ln1_b   = (const float*)d_in[4];
  const float* ln2_g   = (const float*)d_in[5];
  const float* ln2_b   = (const float*)d_in[6];
  const float* rel_bias= (const float*)d_in[7];
  const float* ff_w1   = (const float*)d_in[8];
  const float* ff_b1   = (const float*)d_in[9];
  const float* ff_w2   = (const float*)d_in[10];
  const float* ff_b2   = (const float*)d_in[11];
  const int*   Wp      = (const int*)d_in[13];
  const int*   topk_p  = (const int*)d_in[14];

  float* h = (float*)d_out;   // residual stream lives in d_out

  char* ws = (char*)d_ws;
  float* n_buf = (float*)ws;                 ws += (size_t)S_TOT * DIMC * 4;
  float* qkv   = (float*)ws;
  float* y1    = (float*)ws;                 // alias: y1 overlaps qkv+Qt (both dead by FF1)
                                             ws += (size_t)S_TOT * 3 * INNERC * 4;
  float* Qt    = (float*)ws;                 ws += (size_t)NHC * S_TOT * DHC * 4;
  float* Kt    = (float*)ws;                 ws += (size_t)NHC * S_TOT * DHC * 4;
  float* Vt    = (float*)ws;                 ws += (size_t)NHC * S_TOT * DHC * 4;
  float* attn_out = (float*)ws;              ws += (size_t)S_TOT * INNERC * 4;

  copy_kernel<<<(S_TOT * DIMC + 255) / 256, 256, 0, stream>>>(x, h, S_TOT * DIMC);

  for (int l = 0; l < 6; ++l){
    const float* wqkv = W_qkv + (size_t)l * DIMC * 3 * INNERC;
    const float* wo   = W_o   + (size_t)l * INNERC * DIMC;
    const float* w1   = ff_w1 + (size_t)l * DIMC * HIDC;
    const float* w2   = ff_w2 + (size_t)l * HIDC * DIMC;

    ln_kernel<<<S_TOT, 128, 0, stream>>>(h, ln1_g + l * DIMC, ln1_b + l * DIMC, n_buf);
    gemm_kernel<0, false, false><<<dim3(3 * INNERC / 64, S_TOT / 64), 256, 0, stream>>>(
        n_buf, wqkv, nullptr, nullptr, qkv, S_TOT, 3 * INNERC, DIMC);
    repack_kernel<<<(S_TOT * INNERC + 255) / 256, 256, 0, stream>>>(qkv, Qt, Kt, Vt);
    attn_kernel<<<dim3(S_TOT, NHC), 256, 0, stream>>>(Qt, Kt, Vt, rel_bias, Wp, topk_p, attn_out);
    gemm_kernel<0, false, true><<<dim3(DIMC / 64, S_TOT / 64), 256, 0, stream>>>(
        attn_out, wo, nullptr, h, h, S_TOT, DIMC, INNERC);
    ln_kernel<<<S_TOT, 128, 0, stream>>>(h, ln2_g + l * DIMC, ln2_b + l * DIMC, n_buf);
    gemm_kernel<1, true, false><<<dim3(HIDC / 64, S_TOT / 64), 256, 0, stream>>>(
        n_buf, w1, ff_b1 + l * HIDC, nullptr, y1, S_TOT, HIDC, DIMC);
    gemm_kernel<0, true, true><<<dim3(DIMC / 64, S_TOT / 64), 256, 0, stream>>>(
        y1, w2, ff_b2 + l * DIMC, h, h, S_TOT, DIMC, HIDC);
  }
}

// Round 4
// 1239.293 us; speedup vs baseline: 4.1987x; 2.2955x over previous
//
#include <hip/hip_runtime.h>
#include <float.h>

#define DIMC 384
#define NHC 6
#define DHC 64
#define INNERC 384
#define HIDC 1536
#define S_TOT 1600
#define QBLK 16
#define CAPC 48
#define SP 1608   // score row pitch (ushorts), padded to stagger banks

typedef unsigned short u16;
typedef __attribute__((ext_vector_type(8))) short bf16x8;
typedef __attribute__((ext_vector_type(4))) float f32x4;

__device__ __forceinline__ u16 f2bf(float x){
  unsigned u = __float_as_uint(x);
  return (u16)((u + 0x7FFFu + ((u >> 16) & 1u)) >> 16);
}
__device__ __forceinline__ float bf2f(u16 h){
  return __uint_as_float(((unsigned)h) << 16);
}
__device__ __forceinline__ float waveReduceSumF(float v){
  #pragma unroll
  for (int o = 32; o >= 1; o >>= 1) v += __shfl_xor(v, o);
  return v;
}
__device__ __forceinline__ float waveReduceMaxF(float v){
  #pragma unroll
  for (int o = 32; o >= 1; o >>= 1) v = fmaxf(v, __shfl_xor(v, o));
  return v;
}
__device__ __forceinline__ int waveReduceSumI(int v){
  #pragma unroll
  for (int o = 32; o >= 1; o >>= 1) v += __shfl_xor(v, o);
  return v;
}

// ---------------- copy ----------------
__global__ void copy_kernel(const float* __restrict__ in, float* __restrict__ out, int n){
  int i = blockIdx.x * 256 + threadIdx.x;
  if (i < n) out[i] = in[i];
}

// ---------------- bucket table: buck[q][k], once per launch ----------------
__global__ void buck_kernel(const int* __restrict__ Wp, unsigned char* __restrict__ buck){
  int q = blockIdx.x;
  int Wv = *Wp;
  int qv = q / Wv, qh = q % Wv;
  for (int k = threadIdx.x; k < S_TOT; k += 256){
    int kv = k / Wv, kh = k % Wv;
    int dv = kv - qv, dh = kh - qh;
    int man = (dv < 0 ? -dv : dv) + (dh < 0 ? -dh : dh);
    unsigned char bb = (man <= 3) ? (unsigned char)((dv + 3) * 7 + (dh + 3)) : 0;
    buck[(size_t)q * S_TOT + k] = bb;
  }
}

// ---------------- transpose + fp32->bf16 weight convert: out[N][K] = in[K][N] ----------------
__global__ __launch_bounds__(256) void tconv_kernel(const float* __restrict__ in,
                                                    u16* __restrict__ out, int K, int N){
  __shared__ float t[32][33];
  int tx = threadIdx.x & 31, ty = threadIdx.x >> 5;  // ty 0..7
  int k0 = blockIdx.y * 32, n0 = blockIdx.x * 32;
  #pragma unroll
  for (int i = 0; i < 4; ++i)
    t[ty + i * 8][tx] = in[(size_t)(k0 + ty + i * 8) * N + n0 + tx];
  __syncthreads();
  #pragma unroll
  for (int i = 0; i < 4; ++i)
    out[(size_t)(n0 + ty + i * 8) * K + k0 + tx] = f2bf(t[tx][ty + i * 8]);
}

// ---------------- LayerNorm -> bf16 ----------------
__global__ __launch_bounds__(128) void ln_kernel(const float* __restrict__ in,
                                                 const float* __restrict__ g,
                                                 const float* __restrict__ b,
                                                 u16* __restrict__ out){
  int row = blockIdx.x;
  int tid = threadIdx.x;
  const float* rp = in + (size_t)row * DIMC;
  float x0 = rp[tid], x1 = rp[tid + 128], x2 = rp[tid + 256];
  float s  = x0 + x1 + x2;
  float sq = x0 * x0 + x1 * x1 + x2 * x2;
  __shared__ float scr0[2], scr1[2];
  s  = waveReduceSumF(s);
  sq = waveReduceSumF(sq);
  int wid = tid >> 6;
  if ((tid & 63) == 0){ scr0[wid] = s; scr1[wid] = sq; }
  __syncthreads();
  float S1 = scr0[0] + scr0[1];
  float S2 = scr1[0] + scr1[1];
  float mean = S1 * (1.f / DIMC);
  float var  = S2 * (1.f / DIMC) - mean * mean;
  float inv  = rsqrtf(var + 1e-5f);
  u16* op = out + (size_t)row * DIMC;
  op[tid]       = f2bf((x0 - mean) * inv * g[tid]       + b[tid]);
  op[tid + 128] = f2bf((x1 - mean) * inv * g[tid + 128] + b[tid + 128]);
  op[tid + 256] = f2bf((x2 - mean) * inv * g[tid + 256] + b[tid + 256]);
}

// ---------------- bf16 MFMA GEMM: C[M,N] = act(A[M,K] @ Bt[N,K]^T + bias) (+res fp32) ----------------
template<int ACT, bool OUT_BF16, bool HAS_BIAS, bool HAS_RES>
__global__ __launch_bounds__(256) void gemm_bf16(const u16* __restrict__ A,
                                                 const u16* __restrict__ Bt,
                                                 const float* __restrict__ bias,
                                                 const float* __restrict__ res,
                                                 void* __restrict__ Cout,
                                                 int M, int N, int K){
  __shared__ u16 As[64][40];   // pitch 40 bf16 = 80B (16B aligned, banks staggered)
  __shared__ u16 Bs[64][40];
  const int tid = threadIdx.x, lane = tid & 63, wid = tid >> 6;
  const int m0 = blockIdx.y * 64, n0 = blockIdx.x * 64;
  const int wr = (wid >> 1) * 32, wc = (wid & 1) * 32;
  const int sr = tid >> 2, sc8 = (tid & 3) * 8;
  const int frow = lane & 15, fkc = lane >> 4;

  f32x4 acc[2][2] = {};
  for (int k0 = 0; k0 < K; k0 += 32){
    bf16x8 av = *(const bf16x8*)(A  + (size_t)(m0 + sr) * K + k0 + sc8);
    bf16x8 bv = *(const bf16x8*)(Bt + (size_t)(n0 + sr) * K + k0 + sc8);
    __syncthreads();
    *(bf16x8*)&As[sr][sc8] = av;
    *(bf16x8*)&Bs[sr][sc8] = bv;
    __syncthreads();
    bf16x8 af[2], bf_[2];
    #pragma unroll
    for (int rt = 0; rt < 2; ++rt) af[rt]  = *(bf16x8*)&As[wr + rt * 16 + frow][fkc * 8];
    #pragma unroll
    for (int ct = 0; ct < 2; ++ct) bf_[ct] = *(bf16x8*)&Bs[wc + ct * 16 + frow][fkc * 8];
    #pragma unroll
    for (int rt = 0; rt < 2; ++rt)
      #pragma unroll
      for (int ct = 0; ct < 2; ++ct)
        acc[rt][ct] = __builtin_amdgcn_mfma_f32_16x16x32_bf16(af[rt], bf_[ct], acc[rt][ct], 0, 0, 0);
  }
  #pragma unroll
  for (int rt = 0; rt < 2; ++rt)
    #pragma unroll
    for (int ct = 0; ct < 2; ++ct)
      #pragma unroll
      for (int r = 0; r < 4; ++r){
        int row = m0 + wr + rt * 16 + (lane >> 4) * 4 + r;
        int col = n0 + wc + ct * 16 + (lane & 15);
        float v = acc[rt][ct][r];
        if (HAS_BIAS) v += bias[col];
        if (ACT == 1) v = (v >= 0.f) ? v : 0.2f * v;
        if (HAS_RES) v += res[(size_t)row * N + col];
        if (OUT_BF16) ((u16*)Cout)[(size_t)row * N + col] = f2bf(v);
        else          ((float*)Cout)[(size_t)row * N + col] = v;
      }
}

// ---------------- repack: qkv bf16 stride-3 interleave -> per-head [h][s][d] bf16 panels ----------------
__global__ void repack_kernel(const u16* __restrict__ qkv, u16* __restrict__ Qb,
                              u16* __restrict__ Kb, u16* __restrict__ Vb){
  int idx = blockIdx.x * 256 + threadIdx.x;
  if (idx >= S_TOT * INNERC) return;
  int s = idx / INNERC, hd = idx % INNERC;
  int h = hd >> 6, d = hd & 63;
  const u16* p = qkv + (size_t)s * 3 * INNERC + 3 * hd;
  size_t o = (size_t)h * S_TOT * DHC + (size_t)s * DHC + d;
  Qb[o] = p[0];
  Kb[o] = p[1];
  Vb[o] = p[2];
}

// ---------------- fused attention: 16 queries x 1 head per block, 4 waves ----------------
__global__ __launch_bounds__(256) void attn_kernel(const u16* __restrict__ Qbf,
                                                   const u16* __restrict__ Kbf,
                                                   const u16* __restrict__ Vbf,
                                                   const float* __restrict__ rel_bias,
                                                   const unsigned char* __restrict__ buck,
                                                   const int* __restrict__ topk_p,
                                                   u16* __restrict__ attnout){
  const int sq0 = blockIdx.x * QBLK;
  const int hh  = blockIdx.y;
  const int tid = threadIdx.x;
  const int lane = tid & 63;
  const int wid  = tid >> 6;

  __shared__ u16   score[QBLK][SP];       // 51.5 KB
  __shared__ u16   Qt_s[QBLK][72];        // padded pitch, 16B-aligned rows
  __shared__ float qb[QBLK][49];
  __shared__ u16   idxs[4][CAPC];
  __shared__ float pcomp[4][CAPC];

  const u16* Qh = Qbf + (size_t)hh * S_TOT * DHC;
  const u16* Kh = Kbf + (size_t)hh * S_TOT * DHC;
  const u16* Vh = Vbf + (size_t)hh * S_TOT * DHC;

  // stage Q tile
  if (tid < 128){
    int r = tid >> 3, c8 = (tid & 7) * 8;
    *(bf16x8*)&Qt_s[r][c8] = *(const bf16x8*)(Qh + (size_t)(sq0 + r) * DHC + c8);
  }
  __syncthreads();

  // qb[q][nb] = q . rel_bias[nb]  (784 dots of 64, ~3 per thread)
  for (int i = tid; i < QBLK * 49; i += 256){
    int q = i / 49, nb = i % 49;
    const float* rb = rel_bias + (size_t)nb * DHC;
    float s = 0.f;
    #pragma unroll 8
    for (int d = 0; d < DHC; ++d) s += bf2f(Qt_s[q][d]) * rb[d];
    qb[q][nb] = s;
  }
  __syncthreads();

  const float scale = 0.05103103630798287f; // 384^-0.5
  int kwant = *topk_p;
  if (kwant > S_TOT) kwant = S_TOT;

  // A fragments (held whole kernel)
  bf16x8 a0 = *(bf16x8*)&Qt_s[lane & 15][(lane >> 4) * 8];
  bf16x8 a1 = *(bf16x8*)&Qt_s[lane & 15][32 + (lane >> 4) * 8];

  // ---- scores: each wave owns 400 keys = 25 tiles of 16 ----
  for (int t = 0; t < 25; ++t){
    int key0 = wid * 400 + t * 16;
    int key = key0 + (lane & 15);
    const u16* kp = Kh + (size_t)key * DHC + (lane >> 4) * 8;
    bf16x8 b0 = *(const bf16x8*)kp;
    bf16x8 b1 = *(const bf16x8*)(kp + 32);
    f32x4 c = {};
    c = __builtin_amdgcn_mfma_f32_16x16x32_bf16(a0, b0, c, 0, 0, 0);
    c = __builtin_amdgcn_mfma_f32_16x16x32_bf16(a1, b1, c, 0, 0, 0);
    const unsigned char* bp = buck + (size_t)sq0 * S_TOT + key;
    #pragma unroll
    for (int r = 0; r < 4; ++r){
      int q = (lane >> 4) * 4 + r;
      int bb = bp[(size_t)q * S_TOT];
      float s = (c[r] + qb[q][bb]) * scale;
      score[q][key] = f2bf(s);
    }
  }
  __syncthreads();

  // ---- per-wave: queries 4*wid .. 4*wid+3 ----
  for (int qi = 0; qi < 4; ++qi){
    int q = wid * 4 + qi;
    int keys[25];
    float lm = -FLT_MAX;
    #pragma unroll
    for (int i = 0; i < 25; ++i){
      u16 u = score[q][lane + 64 * i];
      keys[i] = (u & 0x8000) ? (u ^ 0xFFFF) : (u | 0x8000);
      lm = fmaxf(lm, bf2f(u));
    }
    float m = waveReduceMaxF(lm);

    // largest T with count(key >= T) >= kwant  (= sortable key of kth largest)
    int lo = 0, hi = 65536;
    while (hi - lo > 1){
      int mid = (lo + hi) >> 1;
      int c = 0;
      #pragma unroll
      for (int i = 0; i < 25; ++i) c += (keys[i] >= mid);
      c = waveReduceSumI(c);
      if (c >= kwant) lo = mid; else hi = mid;
    }
    const int T = lo;

    // compact survivors + denom
    float lsum = 0.f;
    int base = 0;
    #pragma unroll
    for (int i = 0; i < 25; ++i){
      bool sv = (keys[i] >= T);
      unsigned long long mask = __ballot(sv);
      if (sv){
        int pos = base + __popcll(mask & ((1ull << lane) - 1ull));
        float p = __expf(bf2f(score[q][lane + 64 * i]) - m);
        lsum += p;
        if (pos < CAPC){ idxs[wid][pos] = (u16)(lane + 64 * i); pcomp[wid][pos] = p; }
      }
      base += __popcll(mask);
    }
    float denom = waveReduceSumF(lsum);
    int cnt = base;

    // PV: lane = output dim d
    float acc = 0.f;
    if (cnt <= CAPC){
      for (int j = 0; j < cnt; ++j){
        float p = pcomp[wid][j];
        int kk = idxs[wid][j];
        acc += p * bf2f(Vh[(size_t)kk * DHC + lane]);
      }
    } else {
      for (int k = 0; k < S_TOT; ++k){
        u16 u = score[q][k];
        int ky = (u & 0x8000) ? (u ^ 0xFFFF) : (u | 0x8000);
        if (ky >= T) acc += __expf(bf2f(u) - m) * bf2f(Vh[(size_t)k * DHC + lane]);
      }
    }
    attnout[(size_t)(sq0 + q) * INNERC + hh * DHC + lane] = f2bf(acc / denom);
  }
}

extern "C" void kernel_launch(void* const* d_in, const int* in_sizes, int n_in,
                              void* d_out, int out_size, void* d_ws, size_t ws_size,
                              hipStream_t stream) {
  const float* x       = (const float*)d_in[0];
  const float* W_qkv   = (const float*)d_in[1];
  const float* W_o     = (const float*)d_in[2];
  const float* ln1_g   = (const float*)d_in[3];
  const float* ln1_b   = (const float*)d_in[4];
  const float* ln2_g   = (const float*)d_in[5];
  const float* ln2_b   = (const float*)d_in[6];
  const float* rel_bias= (const float*)d_in[7];
  const float* ff_w1   = (const float*)d_in[8];
  const float* ff_b1   = (const float*)d_in[9];
  const float* ff_w2   = (const float*)d_in[10];
  const float* ff_b2   = (const float*)d_in[11];
  const int*   Wp      = (const int*)d_in[13];
  const int*   topk_p  = (const int*)d_in[14];

  float* h = (float*)d_out;   // fp32 residual stream

  char* ws = (char*)d_ws;
  u16* nbf    = (u16*)ws;  ws += (size_t)S_TOT * DIMC * 2;          // 1.23 MB
  u16* qkvbf  = (u16*)ws;  ws += (size_t)S_TOT * 3 * INNERC * 2;    // 3.69 MB
  u16* Qbf    = (u16*)ws;  ws += (size_t)NHC * S_TOT * DHC * 2;     // 1.23 MB
  u16* Kbf    = (u16*)ws;  ws += (size_t)NHC * S_TOT * DHC * 2;
  u16* Vbf    = (u16*)ws;  ws += (size_t)NHC * S_TOT * DHC * 2;
  u16* attnbf = (u16*)ws;  ws += (size_t)S_TOT * INNERC * 2;        // 1.23 MB
  u16* y1bf   = (u16*)ws;  ws += (size_t)S_TOT * HIDC * 2;          // 4.92 MB
  u16* wT     = (u16*)ws;  ws += (size_t)1769472 * 2;               // 3.54 MB
  unsigned char* buck = (unsigned char*)ws; ws += (size_t)S_TOT * S_TOT; // 2.56 MB

  u16* wqkvT = wT;                 // [1152][384]
  u16* woT   = wT + 442368;        // [384][384]
  u16* w1T   = wT + 589824;        // [1536][384]
  u16* w2T   = wT + 1179648;       // [384][1536]

  buck_kernel<<<S_TOT, 256, 0, stream>>>(Wp, buck);
  copy_kernel<<<(S_TOT * DIMC + 255) / 256, 256, 0, stream>>>(x, h, S_TOT * DIMC);

  for (int l = 0; l < 6; ++l){
    const float* wqkv = W_qkv + (size_t)l * DIMC * 3 * INNERC;
    const float* wo   = W_o   + (size_t)l * INNERC * DIMC;
    const float* w1   = ff_w1 + (size_t)l * DIMC * HIDC;
    const float* w2   = ff_w2 + (size_t)l * HIDC * DIMC;

    tconv_kernel<<<dim3(1152/32, 384/32), 256, 0, stream>>>(wqkv, wqkvT, 384, 1152);
    tconv_kernel<<<dim3(384/32,  384/32), 256, 0, stream>>>(wo,   woT,   384, 384);
    tconv_kernel<<<dim3(1536/32, 384/32), 256, 0, stream>>>(w1,   w1T,   384, 1536);
    tconv_kernel<<<dim3(384/32, 1536/32), 256, 0, stream>>>(w2,   w2T,  1536, 384);

    ln_kernel<<<S_TOT, 128, 0, stream>>>(h, ln1_g + l * DIMC, ln1_b + l * DIMC, nbf);
    gemm_bf16<0, true, false, false><<<dim3(18, 25), 256, 0, stream>>>(
        nbf, wqkvT, nullptr, nullptr, qkvbf, S_TOT, 3 * INNERC, DIMC);
    repack_kernel<<<(S_TOT * INNERC + 255) / 256, 256, 0, stream>>>(qkvbf, Qbf, Kbf, Vbf);
    attn_kernel<<<dim3(S_TOT / QBLK, NHC), 256, 0, stream>>>(
        Qbf, Kbf, Vbf, rel_bias, buck, topk_p, attnbf);
    gemm_bf16<0, false, false, true><<<dim3(6, 25), 256, 0, stream>>>(
        attnbf, woT, nullptr, h, h, S_TOT, DIMC, INNERC);
    ln_kernel<<<S_TOT, 128, 0, stream>>>(h, ln2_g + l * DIMC, ln2_b + l * DIMC, nbf);
    gemm_bf16<1, true, true, false><<<dim3(24, 25), 256, 0, stream>>>(
        nbf, w1T, ff_b1 + l * HIDC, nullptr, y1bf, S_TOT, HIDC, DIMC);
    gemm_bf16<0, false, true, true><<<dim3(6, 25), 256, 0, stream>>>(
        y1bf, w2T, ff_b2 + l * DIMC, h, h, S_TOT, DIMC, HIDC);
  }
}

// Round 6
// 1232.654 us; speedup vs baseline: 4.2213x; 1.0054x over previous
//
#include <hip/hip_runtime.h>
#include <float.h>

#define DIMC 384
#define NHC 6
#define DHC 64
#define INNERC 384
#define HIDC 1536
#define S_TOT 1600
#define QBLK 16
#define CAPC 64
#define SAK 832     // first key chunk (52 tiles of 16)
#define SBK 768     // second key chunk (48 tiles)
#define SPA 840     // score pitch (u16): 1680B/row -> rows offset by 4 banks

typedef unsigned short u16;
typedef __attribute__((ext_vector_type(8))) short bf16x8;
typedef __attribute__((ext_vector_type(4))) float f32x4;

__device__ __forceinline__ u16 f2bf(float x){
  unsigned u = __float_as_uint(x);
  return (u16)((u + 0x7FFFu + ((u >> 16) & 1u)) >> 16);
}
__device__ __forceinline__ float bf2f(u16 h){
  return __uint_as_float(((unsigned)h) << 16);
}
__device__ __forceinline__ int sortkey(u16 u){
  return (u & 0x8000) ? (int)(u ^ 0xFFFF) : (int)(u | 0x8000);
}
__device__ __forceinline__ u16 invkey(int k){
  return (k & 0x8000) ? (u16)(k & 0x7FFF) : (u16)(k ^ 0xFFFF);
}
__device__ __forceinline__ float waveReduceSumF(float v){
  #pragma unroll
  for (int o = 32; o >= 1; o >>= 1) v += __shfl_xor(v, o);
  return v;
}

// ---------------- copy ----------------
__global__ void copy_kernel(const float* __restrict__ in, float* __restrict__ out, int n){
  int i = blockIdx.x * 256 + threadIdx.x;
  if (i < n) out[i] = in[i];
}

// ---------------- bucket table ----------------
__global__ void buck_kernel(const int* __restrict__ Wp, unsigned char* __restrict__ buck){
  int q = blockIdx.x;
  int Wv = *Wp;
  int qv = q / Wv, qh = q % Wv;
  for (int k = threadIdx.x; k < S_TOT; k += 256){
    int kv = k / Wv, kh = k % Wv;
    int dv = kv - qv, dh = kh - qh;
    int man = (dv < 0 ? -dv : dv) + (dh < 0 ? -dh : dh);
    unsigned char bb = (man <= 3) ? (unsigned char)((dv + 3) * 7 + (dh + 3)) : 0;
    buck[(size_t)q * S_TOT + k] = bb;
  }
}

// ---------------- fused transpose+convert for all 4 layer weights ----------------
struct TC4Args {
  const float *in0, *in1, *in2, *in3;
  u16 *out0, *out1, *out2, *out3;
};
__global__ __launch_bounds__(256) void tconv4_kernel(TC4Args a){
  int b = blockIdx.x;
  const float* in; u16* out; int K, N, t;
  if (b < 432)      { in = a.in0; out = a.out0; K = 384;  N = 1152; t = b; }
  else if (b < 576) { in = a.in1; out = a.out1; K = 384;  N = 384;  t = b - 432; }
  else if (b < 1152){ in = a.in2; out = a.out2; K = 384;  N = 1536; t = b - 576; }
  else              { in = a.in3; out = a.out3; K = 1536; N = 384;  t = b - 1152; }
  int nx = N >> 5;
  int bx = t % nx, by = t / nx;
  __shared__ float tt[32][33];
  int tx = threadIdx.x & 31, ty = threadIdx.x >> 5;
  int k0 = by * 32, n0 = bx * 32;
  #pragma unroll
  for (int i = 0; i < 4; ++i)
    tt[ty + i * 8][tx] = in[(size_t)(k0 + ty + i * 8) * N + n0 + tx];
  __syncthreads();
  #pragma unroll
  for (int i = 0; i < 4; ++i)
    out[(size_t)(n0 + ty + i * 8) * K + k0 + tx] = f2bf(tt[tx][ty + i * 8]);
}

// ---------------- LayerNorm -> bf16 ----------------
__global__ __launch_bounds__(128) void ln_kernel(const float* __restrict__ in,
                                                 const float* __restrict__ g,
                                                 const float* __restrict__ b,
                                                 u16* __restrict__ out){
  int row = blockIdx.x;
  int tid = threadIdx.x;
  const float* rp = in + (size_t)row * DIMC;
  float x0 = rp[tid], x1 = rp[tid + 128], x2 = rp[tid + 256];
  float s  = x0 + x1 + x2;
  float sq = x0 * x0 + x1 * x1 + x2 * x2;
  __shared__ float scr0[2], scr1[2];
  s  = waveReduceSumF(s);
  sq = waveReduceSumF(sq);
  int wid = tid >> 6;
  if ((tid & 63) == 0){ scr0[wid] = s; scr1[wid] = sq; }
  __syncthreads();
  float S1 = scr0[0] + scr0[1];
  float S2 = scr1[0] + scr1[1];
  float mean = S1 * (1.f / DIMC);
  float var  = S2 * (1.f / DIMC) - mean * mean;
  float inv  = rsqrtf(var + 1e-5f);
  u16* op = out + (size_t)row * DIMC;
  op[tid]       = f2bf((x0 - mean) * inv * g[tid]       + b[tid]);
  op[tid + 128] = f2bf((x1 - mean) * inv * g[tid + 128] + b[tid + 128]);
  op[tid + 256] = f2bf((x2 - mean) * inv * g[tid + 256] + b[tid + 256]);
}

// ---------------- bf16 MFMA GEMM ----------------
template<int ACT, bool OUT_BF16, bool HAS_BIAS, bool HAS_RES>
__global__ __launch_bounds__(256) void gemm_bf16(const u16* __restrict__ A,
                                                 const u16* __restrict__ Bt,
                                                 const float* __restrict__ bias,
                                                 const float* __restrict__ res,
                                                 void* __restrict__ Cout,
                                                 int M, int N, int K){
  __shared__ u16 As[64][40];
  __shared__ u16 Bs[64][40];
  const int tid = threadIdx.x, lane = tid & 63, wid = tid >> 6;
  const int m0 = blockIdx.y * 64, n0 = blockIdx.x * 64;
  const int wr = (wid >> 1) * 32, wc = (wid & 1) * 32;
  const int sr = tid >> 2, sc8 = (tid & 3) * 8;
  const int frow = lane & 15, fkc = lane >> 4;

  f32x4 acc[2][2] = {};
  for (int k0 = 0; k0 < K; k0 += 32){
    bf16x8 av = *(const bf16x8*)(A  + (size_t)(m0 + sr) * K + k0 + sc8);
    bf16x8 bv = *(const bf16x8*)(Bt + (size_t)(n0 + sr) * K + k0 + sc8);
    __syncthreads();
    *(bf16x8*)&As[sr][sc8] = av;
    *(bf16x8*)&Bs[sr][sc8] = bv;
    __syncthreads();
    bf16x8 af[2], bf_[2];
    #pragma unroll
    for (int rt = 0; rt < 2; ++rt) af[rt]  = *(bf16x8*)&As[wr + rt * 16 + frow][fkc * 8];
    #pragma unroll
    for (int ct = 0; ct < 2; ++ct) bf_[ct] = *(bf16x8*)&Bs[wc + ct * 16 + frow][fkc * 8];
    #pragma unroll
    for (int rt = 0; rt < 2; ++rt)
      #pragma unroll
      for (int ct = 0; ct < 2; ++ct)
        acc[rt][ct] = __builtin_amdgcn_mfma_f32_16x16x32_bf16(af[rt], bf_[ct], acc[rt][ct], 0, 0, 0);
  }
  #pragma unroll
  for (int rt = 0; rt < 2; ++rt)
    #pragma unroll
    for (int ct = 0; ct < 2; ++ct)
      #pragma unroll
      for (int r = 0; r < 4; ++r){
        int row = m0 + wr + rt * 16 + (lane >> 4) * 4 + r;
        int col = n0 + wc + ct * 16 + (lane & 15);
        float v = acc[rt][ct][r];
        if (HAS_BIAS) v += bias[col];
        if (ACT == 1) v = (v >= 0.f) ? v : 0.2f * v;
        if (HAS_RES) v += res[(size_t)row * N + col];
        if (OUT_BF16) ((u16*)Cout)[(size_t)row * N + col] = f2bf(v);
        else          ((float*)Cout)[(size_t)row * N + col] = v;
      }
}

// ---------------- repack qkv -> per-head panels ----------------
__global__ void repack_kernel(const u16* __restrict__ qkv, u16* __restrict__ Qb,
                              u16* __restrict__ Kb, u16* __restrict__ Vb){
  int idx = blockIdx.x * 256 + threadIdx.x;
  if (idx >= S_TOT * INNERC) return;
  int s = idx / INNERC, hd = idx % INNERC;
  int h = hd >> 6, d = hd & 63;
  const u16* p = qkv + (size_t)s * 3 * INNERC + 3 * hd;
  size_t o = (size_t)h * S_TOT * DHC + (size_t)s * DHC + d;
  Qb[o] = p[0];
  Kb[o] = p[1];
  Vb[o] = p[2];
}

// ---------------- fused attention: 16 q x 1 head per block, 4 waves, split-K LDS ----------------
__global__ __launch_bounds__(256, 4) void attn_kernel(const u16* __restrict__ Qbf,
                                                      const u16* __restrict__ Kbf,
                                                      const u16* __restrict__ Vbf,
                                                      const float* __restrict__ rel_bias,
                                                      const unsigned char* __restrict__ buck,
                                                      const int* __restrict__ topk_p,
                                                      u16* __restrict__ attnout){
  const int sq0 = blockIdx.x * QBLK;
  const int hh  = blockIdx.y;
  const int tid = threadIdx.x;
  const int lane = tid & 63;
  const int wid  = tid >> 6;

  __shared__ u16   score[QBLK][SPA];     // 26.9 KB, reused for both key chunks
  __shared__ u16   Qt_s[QBLK][72];
  __shared__ float qb[QBLK][49];
  __shared__ u16   idxs[4][CAPC];
  __shared__ float pcomp[4][CAPC];

  const u16* Qh = Qbf + (size_t)hh * S_TOT * DHC;
  const u16* Kh = Kbf + (size_t)hh * S_TOT * DHC;
  const u16* Vh = Vbf + (size_t)hh * S_TOT * DHC;

  if (tid < 128){
    int r = tid >> 3, c8 = (tid & 7) * 8;
    *(bf16x8*)&Qt_s[r][c8] = *(const bf16x8*)(Qh + (size_t)(sq0 + r) * DHC + c8);
  }
  __syncthreads();

  for (int i = tid; i < QBLK * 49; i += 256){
    int q = i / 49, nb = i % 49;
    const float* rb = rel_bias + (size_t)nb * DHC;
    float s = 0.f;
    #pragma unroll 8
    for (int d = 0; d < DHC; ++d) s += bf2f(Qt_s[q][d]) * rb[d];
    qb[q][nb] = s;
  }
  __syncthreads();

  const float scale = 0.05103103630798287f; // 384^-0.5
  int kwant = *topk_p;
  if (kwant > S_TOT) kwant = S_TOT;

  // ---- phase 1a: keys [0, 832), 13 tiles per wave ----
  {
    bf16x8 a0 = *(bf16x8*)&Qt_s[lane & 15][(lane >> 4) * 8];
    bf16x8 a1 = *(bf16x8*)&Qt_s[lane & 15][32 + (lane >> 4) * 8];
    for (int t = 0; t < 13; ++t){
      int key = (wid * 13 + t) * 16 + (lane & 15);
      const u16* kp = Kh + (size_t)key * DHC + (lane >> 4) * 8;
      bf16x8 b0 = *(const bf16x8*)kp;
      bf16x8 b1 = *(const bf16x8*)(kp + 32);
      f32x4 c = {};
      c = __builtin_amdgcn_mfma_f32_16x16x32_bf16(a0, b0, c, 0, 0, 0);
      c = __builtin_amdgcn_mfma_f32_16x16x32_bf16(a1, b1, c, 0, 0, 0);
      const unsigned char* bp = buck + (size_t)sq0 * S_TOT + key;
      #pragma unroll
      for (int r = 0; r < 4; ++r){
        int q = (lane >> 4) * 4 + r;
        int bb = bp[(size_t)q * S_TOT];
        score[q][key] = f2bf((c[r] + qb[q][bb]) * scale);
      }
    }
  }
  __syncthreads();

  // ---- phase 2a: pull chunk-A keys into regs (packed q-pairs) ----
  unsigned pk0[25], pk1[25];
  float lm0 = -FLT_MAX, lm1 = -FLT_MAX, lm2 = -FLT_MAX, lm3 = -FLT_MAX;
  const int qw = wid * 4;
  #pragma unroll
  for (int i = 0; i < 13; ++i){
    int col = lane + 64 * i;
    u16 u0 = score[qw + 0][col], u1 = score[qw + 1][col];
    u16 u2 = score[qw + 2][col], u3 = score[qw + 3][col];
    lm0 = fmaxf(lm0, bf2f(u0)); lm1 = fmaxf(lm1, bf2f(u1));
    lm2 = fmaxf(lm2, bf2f(u2)); lm3 = fmaxf(lm3, bf2f(u3));
    pk0[i] = (unsigned)sortkey(u0) | ((unsigned)sortkey(u1) << 16);
    pk1[i] = (unsigned)sortkey(u2) | ((unsigned)sortkey(u3) << 16);
  }
  __syncthreads();

  // ---- phase 1b: keys [832, 1600), 12 tiles per wave ----
  {
    bf16x8 a0 = *(bf16x8*)&Qt_s[lane & 15][(lane >> 4) * 8];
    bf16x8 a1 = *(bf16x8*)&Qt_s[lane & 15][32 + (lane >> 4) * 8];
    for (int t = 0; t < 12; ++t){
      int key = SAK + (wid * 12 + t) * 16 + (lane & 15);
      const u16* kp = Kh + (size_t)key * DHC + (lane >> 4) * 8;
      bf16x8 b0 = *(const bf16x8*)kp;
      bf16x8 b1 = *(const bf16x8*)(kp + 32);
      f32x4 c = {};
      c = __builtin_amdgcn_mfma_f32_16x16x32_bf16(a0, b0, c, 0, 0, 0);
      c = __builtin_amdgcn_mfma_f32_16x16x32_bf16(a1, b1, c, 0, 0, 0);
      const unsigned char* bp = buck + (size_t)sq0 * S_TOT + key;
      #pragma unroll
      for (int r = 0; r < 4; ++r){
        int q = (lane >> 4) * 4 + r;
        int bb = bp[(size_t)q * S_TOT];
        score[q][key - SAK] = f2bf((c[r] + qb[q][bb]) * scale);
      }
    }
  }
  __syncthreads();

  // ---- phase 2b: pull chunk-B keys ----
  #pragma unroll
  for (int i2 = 0; i2 < 12; ++i2){
    int col = lane + 64 * i2;
    u16 u0 = score[qw + 0][col], u1 = score[qw + 1][col];
    u16 u2 = score[qw + 2][col], u3 = score[qw + 3][col];
    lm0 = fmaxf(lm0, bf2f(u0)); lm1 = fmaxf(lm1, bf2f(u1));
    lm2 = fmaxf(lm2, bf2f(u2)); lm3 = fmaxf(lm3, bf2f(u3));
    pk0[13 + i2] = (unsigned)sortkey(u0) | ((unsigned)sortkey(u1) << 16);
    pk1[13 + i2] = (unsigned)sortkey(u2) | ((unsigned)sortkey(u3) << 16);
  }

  // ---- 4-way interleaved max reduce ----
  #pragma unroll
  for (int o = 32; o >= 1; o >>= 1){
    lm0 = fmaxf(lm0, __shfl_xor(lm0, o));
    lm1 = fmaxf(lm1, __shfl_xor(lm1, o));
    lm2 = fmaxf(lm2, __shfl_xor(lm2, o));
    lm3 = fmaxf(lm3, __shfl_xor(lm3, o));
  }
  float mfin[4] = {lm0, lm1, lm2, lm3};

  // ---- 4-way interleaved binary search for kth-largest key ----
  int lo[4] = {0, 0, 0, 0}, hi[4] = {65536, 65536, 65536, 65536};
  for (int it = 0; it < 16; ++it){
    int m0 = (lo[0] + hi[0]) >> 1, m1 = (lo[1] + hi[1]) >> 1;
    int m2 = (lo[2] + hi[2]) >> 1, m3 = (lo[3] + hi[3]) >> 1;
    int c0 = 0, c1 = 0, c2 = 0, c3 = 0;
    #pragma unroll
    for (int i = 0; i < 25; ++i){
      unsigned r0 = pk0[i], r1 = pk1[i];
      c0 += ((int)(r0 & 0xFFFFu) >= m0);
      c1 += ((int)(r0 >> 16)     >= m1);
      c2 += ((int)(r1 & 0xFFFFu) >= m2);
      c3 += ((int)(r1 >> 16)     >= m3);
    }
    #pragma unroll
    for (int o = 32; o >= 1; o >>= 1){
      c0 += __shfl_xor(c0, o); c1 += __shfl_xor(c1, o);
      c2 += __shfl_xor(c2, o); c3 += __shfl_xor(c3, o);
    }
    if (c0 >= kwant) lo[0] = m0; else hi[0] = m0;
    if (c1 >= kwant) lo[1] = m1; else hi[1] = m1;
    if (c2 >= kwant) lo[2] = m2; else hi[2] = m2;
    if (c3 >= kwant) lo[3] = m3; else hi[3] = m3;
  }

  // ---- survivor counts (count >= T), 4-way ----
  int cnt[4];
  {
    int c0 = 0, c1 = 0, c2 = 0, c3 = 0;
    #pragma unroll
    for (int i = 0; i < 25; ++i){
      unsigned r0 = pk0[i], r1 = pk1[i];
      c0 += ((int)(r0 & 0xFFFFu) >= lo[0]);
      c1 += ((int)(r0 >> 16)     >= lo[1]);
      c2 += ((int)(r1 & 0xFFFFu) >= lo[2]);
      c3 += ((int)(r1 >> 16)     >= lo[3]);
    }
    #pragma unroll
    for (int o = 32; o >= 1; o >>= 1){
      c0 += __shfl_xor(c0, o); c1 += __shfl_xor(c1, o);
      c2 += __shfl_xor(c2, o); c3 += __shfl_xor(c3, o);
    }
    cnt[0] = c0; cnt[1] = c1; cnt[2] = c2; cnt[3] = c3;
  }

  // ---- per-query compaction + sparse PV (chunked, exact for any tie count) ----
  #pragma unroll
  for (int qi = 0; qi < 4; ++qi){
    const int Tq = lo[qi];
    const float mq = mfin[qi];
    const int cq = cnt[qi];
    float acc = 0.f, lsum = 0.f;
    bool first = true;
    for (int start = 0; start < cq; start += CAPC){
      int run = 0;
      #pragma unroll
      for (int i = 0; i < 25; ++i){
        unsigned kkp = (qi < 2) ? pk0[i] : pk1[i];
        int key = (qi & 1) ? (int)(kkp >> 16) : (int)(kkp & 0xFFFFu);
        bool sv = (key >= Tq);
        unsigned long long mk = __ballot(sv);
        if (sv){
          int pos = run + __popcll(mk & ((1ull << lane) - 1ull));
          float p = __expf(bf2f(invkey(key)) - mq);
          if (first) lsum += p;
          int rel = pos - start;
          if (rel >= 0 && rel < CAPC){
            int gk = (i < 13) ? (lane + 64 * i) : (SAK + lane + 64 * (i - 13));
            idxs[wid][rel] = (u16)gk;
            pcomp[wid][rel] = p;
          }
        }
        run += __popcll(mk);
      }
      first = false;
      int cn = cq - start; if (cn > CAPC) cn = CAPC;
      for (int j = 0; j < cn; ++j)
        acc += pcomp[wid][j] * bf2f(Vh[(size_t)idxs[wid][j] * DHC + lane]);
    }
    float denom = waveReduceSumF(lsum);
    attnout[(size_t)(sq0 + qw + qi) * INNERC + hh * DHC + lane] = f2bf(acc / denom);
  }
}

extern "C" void kernel_launch(void* const* d_in, const int* in_sizes, int n_in,
                              void* d_out, int out_size, void* d_ws, size_t ws_size,
                              hipStream_t stream) {
  const float* x       = (const float*)d_in[0];
  const float* W_qkv   = (const float*)d_in[1];
  const float* W_o     = (const float*)d_in[2];
  const float* ln1_g   = (const float*)d_in[3];
  const float* ln1_b   = (const float*)d_in[4];
  const float* ln2_g   = (const float*)d_in[5];
  const float* ln2_b   = (const float*)d_in[6];
  const float* rel_bias= (const float*)d_in[7];
  const float* ff_w1   = (const float*)d_in[8];
  const float* ff_b1   = (const float*)d_in[9];
  const float* ff_w2   = (const float*)d_in[10];
  const float* ff_b2   = (const float*)d_in[11];
  const int*   Wp      = (const int*)d_in[13];
  const int*   topk_p  = (const int*)d_in[14];

  float* h = (float*)d_out;   // fp32 residual stream

  char* ws = (char*)d_ws;
  u16* nbf    = (u16*)ws;  ws += (size_t)S_TOT * DIMC * 2;
  u16* qkvbf  = (u16*)ws;  ws += (size_t)S_TOT * 3 * INNERC * 2;
  u16* Qbf    = (u16*)ws;  ws += (size_t)NHC * S_TOT * DHC * 2;
  u16* Kbf    = (u16*)ws;  ws += (size_t)NHC * S_TOT * DHC * 2;
  u16* Vbf    = (u16*)ws;  ws += (size_t)NHC * S_TOT * DHC * 2;
  u16* attnbf = (u16*)ws;  ws += (size_t)S_TOT * INNERC * 2;
  u16* y1bf   = (u16*)ws;  ws += (size_t)S_TOT * HIDC * 2;
  u16* wT     = (u16*)ws;  ws += (size_t)1769472 * 2;
  unsigned char* buck = (unsigned char*)ws; ws += (size_t)S_TOT * S_TOT;

  u16* wqkvT = wT;                 // [1152][384]
  u16* woT   = wT + 442368;        // [384][384]
  u16* w1T   = wT + 589824;        // [1536][384]
  u16* w2T   = wT + 1179648;       // [384][1536]

  buck_kernel<<<S_TOT, 256, 0, stream>>>(Wp, buck);
  copy_kernel<<<(S_TOT * DIMC + 255) / 256, 256, 0, stream>>>(x, h, S_TOT * DIMC);

  for (int l = 0; l < 6; ++l){
    const float* wqkv = W_qkv + (size_t)l * DIMC * 3 * INNERC;
    const float* wo   = W_o   + (size_t)l * INNERC * DIMC;
    const float* w1   = ff_w1 + (size_t)l * DIMC * HIDC;
    const float* w2   = ff_w2 + (size_t)l * HIDC * DIMC;

    TC4Args tc{wqkv, wo, w1, w2, wqkvT, woT, w1T, w2T};
    tconv4_kernel<<<1728, 256, 0, stream>>>(tc);

    ln_kernel<<<S_TOT, 128, 0, stream>>>(h, ln1_g + l * DIMC, ln1_b + l * DIMC, nbf);
    gemm_bf16<0, true, false, false><<<dim3(18, 25), 256, 0, stream>>>(
        nbf, wqkvT, nullptr, nullptr, qkvbf, S_TOT, 3 * INNERC, DIMC);
    repack_kernel<<<(S_TOT * INNERC + 255) / 256, 256, 0, stream>>>(qkvbf, Qbf, Kbf, Vbf);
    attn_kernel<<<dim3(S_TOT / QBLK, NHC), 256, 0, stream>>>(
        Qbf, Kbf, Vbf, rel_bias, buck, topk_p, attnbf);
    gemm_bf16<0, false, false, true><<<dim3(6, 25), 256, 0, stream>>>(
        attnbf, woT, nullptr, h, h, S_TOT, DIMC, INNERC);
    ln_kernel<<<S_TOT, 128, 0, stream>>>(h, ln2_g + l * DIMC, ln2_b + l * DIMC, nbf);
    gemm_bf16<1, true, true, false><<<dim3(24, 25), 256, 0, stream>>>(
        nbf, w1T, ff_b1 + l * HIDC, nullptr, y1bf, S_TOT, HIDC, DIMC);
    gemm_bf16<0, false, true, true><<<dim3(6, 25), 256, 0, stream>>>(
        y1bf, w2T, ff_b2 + l * DIMC, h, h, S_TOT, DIMC, HIDC);
  }
}